// Round 3
// baseline (703.002 us; speedup 1.0000x reference)
//
#include <hip/hip_runtime.h>
#include <hip/hip_bf16.h>

#define BB 8
#define NN 4096
#define FF 128
#define GS 1024

// ---------------------------------------------------------------------------
// Kernel 1: build sortable keys. key = (~sortable_asc(v) << 32) | i so that
// ascending key order == descending value, ascending-index tie-break (exact
// jax.lax.top_k semantics). Keys are all distinct (index in low bits).
// ---------------------------------------------------------------------------
__global__ __launch_bounds__(256) void keys_kernel(const float* __restrict__ x,
                                                   unsigned long long* __restrict__ keys) {
    int gid = blockIdx.x * 256 + threadIdx.x;      // [0, BB*NN)
    int b = gid >> 12;
    int i = gid & (NN - 1);
    float v = x[((size_t)b * NN + i) * FF + (FF - 1)];
    unsigned int bits = __float_as_uint(v);
    unsigned int sv = (bits & 0x80000000u) ? ~bits : (bits | 0x80000000u);
    keys[gid] = ((unsigned long long)(~sv) << 32) | (unsigned int)i;
}

// ---------------------------------------------------------------------------
// Kernel 2: rank by counting, scalar-load edition. b is derived from
// blockIdx only => kb is wave-uniform, and the loop counter is uniform, so
// the key stream compiles to s_load (scalar pipe, free broadcast to 64
// lanes) — no LDS, no barriers. Each thread's count of smaller keys IS its
// position in the jax.lax.top_k output order; ranks < GS emit idx.
// ---------------------------------------------------------------------------
__global__ __launch_bounds__(256) void rank_kernel(const unsigned long long* __restrict__ keys,
                                                   int* __restrict__ idx) {
    const int b = blockIdx.x >> 4;                          // 16 blocks per batch
    const int e = ((blockIdx.x & 15) << 8) + threadIdx.x;   // element in [0, NN)
    const unsigned long long* __restrict__ kb = keys + ((size_t)b << 12);

    const unsigned long long mk = kb[e];                    // vector load, coalesced
    int cnt = 0;
#pragma unroll 16
    for (int t = 0; t < NN; ++t) {
        cnt += (kb[t] < mk) ? 1 : 0;                        // s_load + v_cmp(SGPR,VGPR)
    }
    if (cnt < GS) idx[(b << 10) + cnt] = (int)(mk & 0xFFFFFFFFu);
}

// ---------------------------------------------------------------------------
// Kernel 3: At2[b, j, k] = A[b, idx[b,j], idx[b,k]]  AND  xg[b,j,:] =
// x[b, idx[b,j], :] fused. One block per output row: stage the 16 KB source
// row in LDS (coalesced float4), gather 1024 columns from LDS, write
// coalesced float4. Lanes 0-31 also copy the x row (independent, no sync
// needed before the barrier).
// ---------------------------------------------------------------------------
__global__ __launch_bounds__(256) void gatherAx_kernel(const float* __restrict__ A,
                                                       const float* __restrict__ x,
                                                       const int* __restrict__ idx,
                                                       float* __restrict__ outA,
                                                       float* __restrict__ outx) {
    __shared__ float row[NN];    // 16 KB
    __shared__ int  cols[GS];    //  4 KB
    const int b = blockIdx.x >> 10;
    const int j = blockIdx.x & (GS - 1);
    const int* idxb = idx + (b << 10);
    const int srcrow = idxb[j];

    const float4* a4   = (const float4*)(A + ((size_t)b * NN + srcrow) * NN);
    float4*       row4 = (float4*)row;
    for (int i = threadIdx.x; i < NN / 4; i += 256) row4[i] = a4[i];
    for (int i = threadIdx.x; i < GS; i += 256)     cols[i] = idxb[i];

    if (threadIdx.x < 32) {   // fused x gather: 32 lanes x float4 = 128 floats
        const float4* s4 = (const float4*)(x + ((size_t)b * NN + srcrow) * FF);
        float4*       d4 = (float4*)(outx + (size_t)blockIdx.x * FF);
        d4[threadIdx.x] = s4[threadIdx.x];
    }
    __syncthreads();

    float4* out4 = (float4*)(outA + (size_t)blockIdx.x * GS);
    for (int i = threadIdx.x; i < GS / 4; i += 256) {
        float4 v;
        v.x = row[cols[4 * i + 0]];
        v.y = row[cols[4 * i + 1]];
        v.z = row[cols[4 * i + 2]];
        v.w = row[cols[4 * i + 3]];
        out4[i] = v;
    }
}

extern "C" void kernel_launch(void* const* d_in, const int* in_sizes, int n_in,
                              void* d_out, int out_size, void* d_ws, size_t ws_size,
                              hipStream_t stream) {
    const float* A = (const float*)d_in[0];   // (8, 4096, 4096) fp32
    const float* x = (const float*)d_in[1];   // (8, 4096, 128)  fp32

    float* outA = (float*)d_out;                          // (8, 1024, 1024)
    float* outx = outA + (size_t)BB * GS * GS;            // (8, 1024, 128)

    int* idx = (int*)d_ws;                                          // 32 KB
    unsigned long long* keys = (unsigned long long*)((char*)d_ws + 64 * 1024); // 256 KB

    keys_kernel<<<(BB * NN) / 256, 256, 0, stream>>>(x, keys);
    rank_kernel<<<(BB * NN) / 256, 256, 0, stream>>>(keys, idx);
    gatherAx_kernel<<<BB * GS, 256, 0, stream>>>(A, x, idx, outA, outx);
}

// Round 4
// 632.425 us; speedup vs baseline: 1.1116x; 1.1116x over previous
//
#include <hip/hip_runtime.h>
#include <hip/hip_bf16.h>

#define BB 8
#define NN 4096
#define FF 128
#define GS 1024

// ---------------------------------------------------------------------------
// Kernel 1: build sortable keys + zero the rank counters.
// key = (~sortable_asc(v) << 32) | i  -> ascending 64-bit key order ==
// descending value with ascending-index tie-break (exact jax.lax.top_k
// semantics). Keys are all distinct (index in low bits).
// Counters must be zeroed every call (harness poisons d_ws with 0xAA).
// ---------------------------------------------------------------------------
__global__ __launch_bounds__(256) void keys_kernel(const float* __restrict__ x,
                                                   unsigned long long* __restrict__ keys,
                                                   int* __restrict__ cnt) {
    int gid = blockIdx.x * 256 + threadIdx.x;      // [0, BB*NN)
    int b = gid >> 12;
    int i = gid & (NN - 1);
    float v = x[((size_t)b * NN + i) * FF + (FF - 1)];
    unsigned int bits = __float_as_uint(v);
    unsigned int sv = (bits & 0x80000000u) ? ~bits : (bits | 0x80000000u);
    keys[gid] = ((unsigned long long)(~sv) << 32) | (unsigned int)i;
    cnt[gid] = 0;
}

// ---------------------------------------------------------------------------
// Kernel 2: partial rank counts. Grid = 8 batches x 4 elem-chunks(1024) x
// 8 key-chunks(512) = 256 blocks. Each thread holds 4 own-keys in registers;
// the block's 512-key chunk is staged in 4 KB LDS and streamed via
// ds_read_b128 broadcast (all lanes same address -> conflict-free). One b128
// serves 2 keys x 64 lanes x 4 own-keys = 512 compares. Partial counts are
// atomicAdd'ed into per-element counters (device-scope, low contention).
// ---------------------------------------------------------------------------
__global__ __launch_bounds__(256) void rank_part_kernel(const unsigned long long* __restrict__ keys,
                                                        int* __restrict__ cnt) {
    __shared__ unsigned long long lk[512];         // 4 KB
    const int b  = blockIdx.x >> 5;                // batch
    const int ec = (blockIdx.x >> 3) & 3;          // element chunk (1024 elems)
    const int kc = blockIdx.x & 7;                 // key chunk (512 keys)
    const unsigned long long* kb = keys + ((size_t)b << 12);

    // stage this block's 512-key chunk (coalesced 16B)
    const ulonglong2* g2 = (const ulonglong2*)(kb + (kc << 9));
    ulonglong2*       l2 = (ulonglong2*)lk;
    l2[threadIdx.x] = g2[threadIdx.x];             // 256 threads x 16B = 4 KB

    // own keys: elements ec*1024 + {t, t+256, t+512, t+768} (coalesced)
    const int e0 = (ec << 10) + threadIdx.x;
    unsigned long long m0 = kb[e0];
    unsigned long long m1 = kb[e0 + 256];
    unsigned long long m2 = kb[e0 + 512];
    unsigned long long m3 = kb[e0 + 768];
    __syncthreads();

    int c0 = 0, c1 = 0, c2 = 0, c3 = 0;
#pragma unroll 4
    for (int s = 0; s < 256; ++s) {
        ulonglong2 kk = l2[s];                     // broadcast b128
        c0 += (kk.x < m0) + (kk.y < m0);
        c1 += (kk.x < m1) + (kk.y < m1);
        c2 += (kk.x < m2) + (kk.y < m2);
        c3 += (kk.x < m3) + (kk.y < m3);
    }
    int* cb = cnt + ((size_t)b << 12);
    atomicAdd(&cb[e0],       c0);
    atomicAdd(&cb[e0 + 256], c1);
    atomicAdd(&cb[e0 + 512], c2);
    atomicAdd(&cb[e0 + 768], c3);
}

// ---------------------------------------------------------------------------
// Kernel 3: finalize. rank = total count of smaller keys; ranks < GS are the
// top-GS in exact output order.
// ---------------------------------------------------------------------------
__global__ __launch_bounds__(256) void finalize_kernel(const int* __restrict__ cnt,
                                                       int* __restrict__ idx) {
    int gid = blockIdx.x * 256 + threadIdx.x;      // [0, BB*NN)
    int b = gid >> 12;
    int i = gid & (NN - 1);
    int c = cnt[gid];
    if (c < GS) idx[(b << 10) + c] = i;
}

// ---------------------------------------------------------------------------
// Kernel 4: At2[b, j, k] = A[b, idx[b,j], idx[b,k]]  AND  xg[b,j,:] =
// x[b, idx[b,j], :] fused. One block per output row: stage the 16 KB source
// row in LDS (coalesced float4), gather 1024 columns from LDS, write
// coalesced float4.
// ---------------------------------------------------------------------------
__global__ __launch_bounds__(256) void gatherAx_kernel(const float* __restrict__ A,
                                                       const float* __restrict__ x,
                                                       const int* __restrict__ idx,
                                                       float* __restrict__ outA,
                                                       float* __restrict__ outx) {
    __shared__ float row[NN];    // 16 KB
    __shared__ int  cols[GS];    //  4 KB
    const int b = blockIdx.x >> 10;
    const int j = blockIdx.x & (GS - 1);
    const int* idxb = idx + (b << 10);
    const int srcrow = idxb[j];

    const float4* a4   = (const float4*)(A + ((size_t)b * NN + srcrow) * NN);
    float4*       row4 = (float4*)row;
    for (int i = threadIdx.x; i < NN / 4; i += 256) row4[i] = a4[i];
    for (int i = threadIdx.x; i < GS; i += 256)     cols[i] = idxb[i];

    if (threadIdx.x < 32) {   // fused x gather: 32 lanes x float4 = 128 floats
        const float4* s4 = (const float4*)(x + ((size_t)b * NN + srcrow) * FF);
        float4*       d4 = (float4*)(outx + (size_t)blockIdx.x * FF);
        d4[threadIdx.x] = s4[threadIdx.x];
    }
    __syncthreads();

    float4* out4 = (float4*)(outA + (size_t)blockIdx.x * GS);
    for (int i = threadIdx.x; i < GS / 4; i += 256) {
        float4 v;
        v.x = row[cols[4 * i + 0]];
        v.y = row[cols[4 * i + 1]];
        v.z = row[cols[4 * i + 2]];
        v.w = row[cols[4 * i + 3]];
        out4[i] = v;
    }
}

extern "C" void kernel_launch(void* const* d_in, const int* in_sizes, int n_in,
                              void* d_out, int out_size, void* d_ws, size_t ws_size,
                              hipStream_t stream) {
    const float* A = (const float*)d_in[0];   // (8, 4096, 4096) fp32
    const float* x = (const float*)d_in[1];   // (8, 4096, 128)  fp32

    float* outA = (float*)d_out;                          // (8, 1024, 1024)
    float* outx = outA + (size_t)BB * GS * GS;            // (8, 1024, 128)

    int* idx = (int*)d_ws;                                              // 32 KB
    unsigned long long* keys = (unsigned long long*)((char*)d_ws + (64 << 10));   // 256 KB
    int* cnt = (int*)((char*)d_ws + (512 << 10));                       // 128 KB

    keys_kernel<<<(BB * NN) / 256, 256, 0, stream>>>(x, keys, cnt);
    rank_part_kernel<<<256, 256, 0, stream>>>(keys, cnt);
    finalize_kernel<<<(BB * NN) / 256, 256, 0, stream>>>(cnt, idx);
    gatherAx_kernel<<<BB * GS, 256, 0, stream>>>(A, x, idx, outA, outx);
}